// Round 13
// baseline (1394.214 us; speedup 1.0000x reference)
//
#include <hip/hip_runtime.h>
#include <hip/hip_bf16.h>

typedef short s16x8 __attribute__((ext_vector_type(8)));
typedef float f32x16 __attribute__((ext_vector_type(16)));

namespace {
constexpr int kB = 16;
constexpr int kD = 256;
constexpr int kHW = 16384;
constexpr int kM = 4096;
constexpr int kN = kB * kM;              // 65536 samples
constexpr int kWin = 512;                // columns per window
constexpr int kNWin = kHW / kWin;        // 32 windows
constexpr int kNBlk = kB * kNWin;        // 512 blocks -> 2/CU
constexpr int kKT = 16;                  // K-tile columns
constexpr int kNIter = kWin / kKT;       // 32 iterations
constexpr float kLam = 0.005f;

__device__ __forceinline__ unsigned short f2bf(float f) {
    union { float f; unsigned u; } x{f};
    const unsigned r = x.u + 0x7FFFu + ((x.u >> 16) & 1u);
    return (unsigned short)(r >> 16);
}
__device__ __forceinline__ float bf2f(unsigned short h) {
    union { unsigned u; float f; } x;
    x.u = ((unsigned)h) << 16;
    return x.f;
}
}

// barrier without vmcnt drain (prefetches stay in flight)
#define BAR_SOFT()                                            \
    do {                                                      \
        asm volatile("s_waitcnt lgkmcnt(0)" ::: "memory");    \
        __builtin_amdgcn_s_barrier();                         \
    } while (0)

// ---------------------------------------------------------------------------
// Kernel 1: per-b histogram of flat_idx -> counts c[b][p].
// ---------------------------------------------------------------------------
__global__ __launch_bounds__(256) void count_kernel(
    const int* __restrict__ flat_idx, int* __restrict__ cnt)
{
    __shared__ int h[kHW];
    const int t = threadIdx.x;
    const int b = blockIdx.x;
    for (int i = t; i < kHW; i += 256) h[i] = 0;
    __syncthreads();
    const int* bi = flat_idx + b * kM;
    for (int i = t; i < kM; i += 256) atomicAdd(&h[bi[i]], 1);
    __syncthreads();
    int* dst = cnt + b * kHW;
    for (int i = t; i < kHW; i += 256) dst[i] = h[i];
}

// ---------------------------------------------------------------------------
// Kernel 2: fused stream + weighted Gram + stats (R9 pipeline, 2 blocks/CU).
// 512 blocks (16 b x 32 win of 512 cols) x 512 thr, 32KB LDS, <=128 VGPR ->
// 2 independent blocks/CU: while one block sits at its barrier/vmcnt the
// other issues loads (R9 was 256 blocks = 1/CU, nothing to overlap with).
// Partial Gram emitted in bf16 (64MB total, same as R9's f32 @256 blocks).
// ---------------------------------------------------------------------------
__global__ __launch_bounds__(512, 4) void fused_gram_kernel(
    const float* __restrict__ z, const float* __restrict__ zp,
    const int* __restrict__ cnt,
    __hip_bfloat16* __restrict__ partial, float* __restrict__ statsPart)
{
    __shared__ char smem[32768];   // buf0 @0 (A 8K | B 8K), buf1 @16K

    const int bx = blockIdx.x;
    const int b = bx & (kB - 1);
    const int win0 = (bx >> 4) * kWin;
    const int t = threadIdx.x;
    const int w = t >> 6, lane = t & 63, l31 = lane & 31, half = lane >> 5;
    const int wr = w >> 2;          // 0..1  row block of 128
    const int wc = w & 3;           // 0..3  col block of 64
    const int rbase = t >> 2;       // 0..127 staging row
    const int cg = t & 3;           // 0..3   staging col group (4 f32)

    const float* zb  = z  + (size_t)b * kD * kHW;
    const float* zpb = zp + (size_t)b * kD * kHW;
    const int* cb = cnt + b * kHW;

    f32x16 acc[4][2];
#pragma unroll
    for (int i = 0; i < 4; ++i)
#pragma unroll
        for (int j = 0; j < 2; ++j)
#pragma unroll
            for (int r = 0; r < 16; ++r) acc[i][j][r] = 0.f;

    float sA[2], ssA[2], sB[2], ssB[2];
#pragma unroll
    for (int q = 0; q < 2; ++q) { sA[q] = ssA[q] = sB[q] = ssB[q] = 0.f; }

    // two register sets (static names -> stay in VGPRs)
    float4 va0[2], vb0[2], va1[2], vb1[2];
    int4 ci0, ci1;

#define LOAD_SET(S, kt)                                                     \
    {                                                                       \
        const int base_ = win0 + (kt) * kKT + cg * 4;                       \
        _Pragma("unroll")                                                   \
        for (int q = 0; q < 2; ++q) {                                       \
            const int row_ = rbase + 128 * q;                               \
            va##S[q] = *(const float4*)(zb  + (size_t)row_ * kHW + base_);  \
            vb##S[q] = *(const float4*)(zpb + (size_t)row_ * kHW + base_);  \
        }                                                                   \
        ci##S = *(const int4*)(cb + base_);                                 \
    }

    // LDS fragment-order: element (row,k) at ((k>>3)*256+row)*16 + (k&7)*2
#define CONV_SET(S, buf)                                                    \
    {                                                                       \
        char* As_ = smem + (buf) * 16384;                                   \
        char* Bs_ = As_ + 8192;                                             \
        const float cf_[4] = {(float)ci##S.x, (float)ci##S.y,               \
                              (float)ci##S.z, (float)ci##S.w};              \
        _Pragma("unroll")                                                   \
        for (int q = 0; q < 2; ++q) {                                       \
            const int row_ = rbase + 128 * q;                               \
            const float a_[4]  = {va##S[q].x, va##S[q].y, va##S[q].z, va##S[q].w}; \
            const float bb_[4] = {vb##S[q].x, vb##S[q].y, vb##S[q].z, vb##S[q].w}; \
            ushort4 pa_, pb_;                                               \
            unsigned short* pav_ = (unsigned short*)&pa_;                   \
            unsigned short* pbv_ = (unsigned short*)&pb_;                   \
            _Pragma("unroll")                                               \
            for (int j = 0; j < 4; ++j) {                                   \
                const float a2_ = a_[j] * a_[j];                            \
                const float b2_ = bb_[j] * bb_[j];                          \
                const float wb_ = cf_[j] * bb_[j];                          \
                sA[q] = fmaf(cf_[j], a_[j], sA[q]);                         \
                ssA[q] = fmaf(cf_[j], a2_, ssA[q]);                         \
                sB[q] = fmaf(cf_[j], bb_[j], sB[q]);                        \
                ssB[q] = fmaf(cf_[j], b2_, ssB[q]);                         \
                pav_[j] = f2bf(a_[j]);                                      \
                pbv_[j] = f2bf(wb_);                                        \
            }                                                               \
            const int off_ = (((cg >> 1) * 256 + row_) << 4) + ((cg & 1) << 3); \
            *(unsigned long long*)(As_ + off_) = *(unsigned long long*)&pa_; \
            *(unsigned long long*)(Bs_ + off_) = *(unsigned long long*)&pb_; \
        }                                                                   \
    }

    auto MFMA_STEP = [&](int buf) {
        const char* As = smem + buf * 16384;
        const char* Bs = As + 8192;
        s16x8 af[4], bfr[2];
#pragma unroll
        for (int rt = 0; rt < 4; ++rt) {
            const int row = 128 * wr + 32 * rt + l31;
            af[rt] = *(const s16x8*)(As + ((half * 256 + row) << 4));
        }
#pragma unroll
        for (int ct = 0; ct < 2; ++ct) {
            const int row = 64 * wc + 32 * ct + l31;
            bfr[ct] = *(const s16x8*)(Bs + ((half * 256 + row) << 4));
        }
#pragma unroll
        for (int rt = 0; rt < 4; ++rt)
#pragma unroll
            for (int ct = 0; ct < 2; ++ct)
                acc[rt][ct] = __builtin_amdgcn_mfma_f32_32x32x16_bf16(
                    af[rt], bfr[ct], acc[rt][ct], 0, 0, 0);
    };

    // Prologue
    LOAD_SET(0, 0)
    CONV_SET(0, 0)
    LOAD_SET(1, 1)
    LOAD_SET(0, 2)
    BAR_SOFT();

    for (int kt = 0; kt < kNIter; kt += 2) {
        CONV_SET(1, 1)
        if (kt + 3 < kNIter) LOAD_SET(1, kt + 3)
        MFMA_STEP(0);
        BAR_SOFT();

        if (kt + 2 < kNIter) CONV_SET(0, 0)
        if (kt + 4 < kNIter) LOAD_SET(0, kt + 4)
        MFMA_STEP(1);
        BAR_SOFT();
    }
    __syncthreads();   // full drain before smem reuse

    // 256x256 partial Gram in bf16
    __hip_bfloat16* out = partial + (size_t)bx * (kD * kD);
#pragma unroll
    for (int rt = 0; rt < 4; ++rt)
#pragma unroll
        for (int ct = 0; ct < 2; ++ct)
#pragma unroll
            for (int r = 0; r < 16; ++r) {
                const int row = 128 * wr + 32 * rt + (r & 3) + 8 * (r >> 2) + 4 * half;
                const int col = 64 * wc + 32 * ct + l31;
                ((unsigned short*)out)[row * kD + col] = f2bf(acc[rt][ct][r]);
            }

    // stats partial reduce via (dead) LDS: sd[256 rows][4 cg][4 kinds] = 16KB
    float* sd = (float*)smem;
#pragma unroll
    for (int q = 0; q < 2; ++q) {
        const int row = rbase + 128 * q;
        float* p = sd + (row * 4 + cg) * 4;
        p[0] = sA[q]; p[1] = ssA[q]; p[2] = sB[q]; p[3] = ssB[q];
    }
    __syncthreads();
    {
        const int row = t >> 1;
        const int pair = t & 1;
        float a0 = 0.f, a1 = 0.f;
#pragma unroll
        for (int g = 0; g < 4; ++g) {
            a0 += sd[(row * 4 + g) * 4 + 2 * pair];
            a1 += sd[(row * 4 + g) * 4 + 2 * pair + 1];
        }
        float* p = statsPart + ((size_t)bx * kD + row) * 4;
        p[2 * pair] = a0;
        p[2 * pair + 1] = a1;
    }
#undef LOAD_SET
#undef CONV_SET
}

// ---------------------------------------------------------------------------
// Kernel 3: reduce bf16 partial Grams (512 x [256][256]) -> G f32;
// statsPart -> statsRed.  Grid 256 (one block per output row d).
// Thread layout: 32 e-threads (8 cols each, 16B loads) x 8 c-groups.
// ---------------------------------------------------------------------------
__global__ __launch_bounds__(256) void reduce_gram_kernel(
    const __hip_bfloat16* __restrict__ partial, const float* __restrict__ statsPart,
    float* __restrict__ G, float* __restrict__ statsRed)
{
    const int d = blockIdx.x;
    const int t = threadIdx.x;
    const int eg = t & 31;          // e-group: cols eg*8..+8
    const int cgp = t >> 5;         // 0..7

    float fa[8];
#pragma unroll
    for (int j = 0; j < 8; ++j) fa[j] = 0.f;
    const unsigned short* pbase = (const unsigned short*)partial + d * kD + eg * 8;
    for (int c0 = 0; c0 < kNBlk / 8; ++c0) {
        const int c = c0 * 8 + cgp;
        const s16x8 v = *(const s16x8*)(pbase + (size_t)c * (kD * kD));
#pragma unroll
        for (int j = 0; j < 8; ++j)
            fa[j] += bf2f(((const unsigned short*)&v)[j]);
    }
    __shared__ float sd[8][256];
#pragma unroll
    for (int j = 0; j < 8; ++j) sd[cgp][eg * 8 + j] = fa[j];
    __syncthreads();
    {
        const int e = t;
        float s = 0.f;
#pragma unroll
        for (int g = 0; g < 8; ++g) s += sd[g][e];
        G[d * kD + e] = s;
    }

    // stats: thread t accumulates slabs t, t+256 of row d, then reduce
    float x0 = 0.f, x1 = 0.f, x2 = 0.f, x3 = 0.f;
#pragma unroll
    for (int c = t; c < kNBlk; c += 256) {
        const float4 v = *(const float4*)(statsPart + ((size_t)c * kD + d) * 4);
        x0 += v.x; x1 += v.y; x2 += v.z; x3 += v.w;
    }
#pragma unroll
    for (int o = 32; o; o >>= 1) {
        x0 += __shfl_down(x0, o);
        x1 += __shfl_down(x1, o);
        x2 += __shfl_down(x2, o);
        x3 += __shfl_down(x3, o);
    }
    __shared__ float r[4][4];
    if ((t & 63) == 0) {
        r[t >> 6][0] = x0; r[t >> 6][1] = x1;
        r[t >> 6][2] = x2; r[t >> 6][3] = x3;
    }
    __syncthreads();
    if (t < 4) {
        statsRed[d * 4 + t] = r[0][t] + r[1][t] + r[2][t] + r[3][t];
    }
}

// ---------------------------------------------------------------------------
// Kernel 4: final loss (single block).
// ---------------------------------------------------------------------------
__global__ __launch_bounds__(256) void loss_kernel(
    const float* __restrict__ G, const float* __restrict__ statsRed,
    float* __restrict__ out)
{
    __shared__ float muA[kD], isA[kD], muB[kD], isB[kD];
    const int t = threadIdx.x;
    const float4 v = *(const float4*)(statsRed + t * 4);
    const float n = (float)kN;
    const float mA = v.x / n, mB = v.z / n;
    const float vA = (v.y - n * mA * mA) / (n - 1.f);
    const float vB = (v.w - n * mB * mB) / (n - 1.f);
    const float sdA = fmaxf(sqrtf(fmaxf(vA, 0.f)), 1e-6f);
    const float sdB = fmaxf(sqrtf(fmaxf(vB, 0.f)), 1e-6f);
    muA[t] = mA; isA[t] = 1.f / sdA;
    muB[t] = mB; isB[t] = 1.f / sdB;
    __syncthreads();

    float acc = 0.f;
    for (int d = 0; d < kD; ++d) {
        const int e = t;
        const float c = (G[d * kD + e] / n - muA[d] * muB[e]) * isA[d] * isB[e];
        if (d == e) { const float u = 1.f - c; acc += u * u; }
        else        { acc += kLam * c * c; }
    }
#pragma unroll
    for (int o = 32; o; o >>= 1) acc += __shfl_down(acc, o);
    __shared__ float r[4];
    if ((t & 63) == 0) r[t >> 6] = acc;
    __syncthreads();
    if (t == 0) out[0] = r[0] + r[1] + r[2] + r[3];
}

// ---------------------------------------------------------------------------
extern "C" void kernel_launch(void* const* d_in, const int* in_sizes, int n_in,
                              void* d_out, int out_size, void* d_ws, size_t ws_size,
                              hipStream_t stream) {
    const float* z  = (const float*)d_in[0];
    const float* zp = (const float*)d_in[1];
    const int* flat_idx = (const int*)d_in[2];
    float* out = (float*)d_out;

    char* ws = (char*)d_ws;
    // ws layout:
    //   [0, 1MB)        counts  int [16][16384]
    //   [1MB, 3MB)      statsPart f32 [512][256][4]
    //   [3MB, +4K)      statsRed f32 [256][4]
    //   [3MB+64K,+256K) G f32 [256][256]
    //   [16MB, 80MB)    partial bf16 [512][256][256]
    int* cnt = (int*)ws;
    float* statsPart = (float*)(ws + (size_t)1 * 1024 * 1024);
    float* statsRed  = (float*)(ws + (size_t)3 * 1024 * 1024);
    float* G = (float*)(ws + (size_t)3 * 1024 * 1024 + 64 * 1024);
    __hip_bfloat16* partial = (__hip_bfloat16*)(ws + (size_t)16 * 1024 * 1024);

    count_kernel<<<kB, 256, 0, stream>>>(flat_idx, cnt);
    fused_gram_kernel<<<kNBlk, 512, 0, stream>>>(z, zp, cnt, partial, statsPart);
    reduce_gram_kernel<<<kD, 256, 0, stream>>>(partial, statsPart, G, statsRed);
    loss_kernel<<<1, 256, 0, stream>>>(G, statsRed, out);
}

// Round 14
// 176.124 us; speedup vs baseline: 7.9161x; 7.9161x over previous
//
#include <hip/hip_runtime.h>
#include <hip/hip_bf16.h>

typedef short s16x8 __attribute__((ext_vector_type(8)));
typedef float f32x16 __attribute__((ext_vector_type(16)));

namespace {
constexpr int kB = 16;
constexpr int kD = 256;
constexpr int kHW = 16384;
constexpr int kM = 4096;
constexpr int kN = kB * kM;              // 65536 samples
constexpr int kWin = 512;                // columns per window
constexpr int kNWin = kHW / kWin;        // 32 windows
constexpr int kNBlk = kB * kNWin;        // 512 blocks -> 2/CU
constexpr int kKT = 16;                  // K-tile columns
constexpr int kNIter = kWin / kKT;       // 32 iterations
constexpr float kLam = 0.005f;

__device__ __forceinline__ unsigned short f2bf(float f) {
    union { float f; unsigned u; } x{f};
    const unsigned r = x.u + 0x7FFFu + ((x.u >> 16) & 1u);
    return (unsigned short)(r >> 16);
}
__device__ __forceinline__ float bf2f(unsigned short h) {
    union { unsigned u; float f; } x;
    x.u = ((unsigned)h) << 16;
    return x.f;
}
}

// barrier without vmcnt drain (prefetches stay in flight)
#define BAR_SOFT()                                            \
    do {                                                      \
        asm volatile("s_waitcnt lgkmcnt(0)" ::: "memory");    \
        __builtin_amdgcn_s_barrier();                         \
    } while (0)

// ---------------------------------------------------------------------------
// Kernel 1: per-b histogram of flat_idx -> counts c[b][p].
// ---------------------------------------------------------------------------
__global__ __launch_bounds__(256) void count_kernel(
    const int* __restrict__ flat_idx, int* __restrict__ cnt)
{
    __shared__ int h[kHW];
    const int t = threadIdx.x;
    const int b = blockIdx.x;
    for (int i = t; i < kHW; i += 256) h[i] = 0;
    __syncthreads();
    const int* bi = flat_idx + b * kM;
    for (int i = t; i < kM; i += 256) atomicAdd(&h[bi[i]], 1);
    __syncthreads();
    int* dst = cnt + b * kHW;
    for (int i = t; i < kHW; i += 256) dst[i] = h[i];
}

// ---------------------------------------------------------------------------
// Kernel 2: fused stream + weighted Gram + stats (R9 pipeline, grid 512).
// launch_bounds(512,2): compiler uses ~124 VGPR (R9 codegen, no spill);
// 124*4 <= 512 so 4 waves/SIMD fit -> 2 independent blocks/CU from the
// 512-block grid.  While one block waits at its barrier the other issues
// loads -> more outstanding HBM requests per CU.
// ---------------------------------------------------------------------------
__global__ __launch_bounds__(512, 2) void fused_gram_kernel(
    const float* __restrict__ z, const float* __restrict__ zp,
    const int* __restrict__ cnt,
    __hip_bfloat16* __restrict__ partial, float* __restrict__ statsPart)
{
    __shared__ char smem[32768];   // buf0 @0 (A 8K | B 8K), buf1 @16K

    const int bx = blockIdx.x;
    const int b = bx & (kB - 1);
    const int win0 = (bx >> 4) * kWin;
    const int t = threadIdx.x;
    const int w = t >> 6, lane = t & 63, l31 = lane & 31, half = lane >> 5;
    const int wr = w >> 2;          // 0..1  row block of 128
    const int wc = w & 3;           // 0..3  col block of 64
    const int rbase = t >> 2;       // 0..127 staging row
    const int cg = t & 3;           // 0..3   staging col group (4 f32)

    const float* zb  = z  + (size_t)b * kD * kHW;
    const float* zpb = zp + (size_t)b * kD * kHW;
    const int* cb = cnt + b * kHW;

    f32x16 acc[4][2];
#pragma unroll
    for (int i = 0; i < 4; ++i)
#pragma unroll
        for (int j = 0; j < 2; ++j)
#pragma unroll
            for (int r = 0; r < 16; ++r) acc[i][j][r] = 0.f;

    float sA[2], ssA[2], sB[2], ssB[2];
#pragma unroll
    for (int q = 0; q < 2; ++q) { sA[q] = ssA[q] = sB[q] = ssB[q] = 0.f; }

    // two register sets (static names -> stay in VGPRs)
    float4 va0[2], vb0[2], va1[2], vb1[2];
    int4 ci0, ci1;

#define LOAD_SET(S, kt)                                                     \
    {                                                                       \
        const int base_ = win0 + (kt) * kKT + cg * 4;                       \
        _Pragma("unroll")                                                   \
        for (int q = 0; q < 2; ++q) {                                       \
            const int row_ = rbase + 128 * q;                               \
            va##S[q] = *(const float4*)(zb  + (size_t)row_ * kHW + base_);  \
            vb##S[q] = *(const float4*)(zpb + (size_t)row_ * kHW + base_);  \
        }                                                                   \
        ci##S = *(const int4*)(cb + base_);                                 \
    }

    // LDS fragment-order: element (row,k) at ((k>>3)*256+row)*16 + (k&7)*2
#define CONV_SET(S, buf)                                                    \
    {                                                                       \
        char* As_ = smem + (buf) * 16384;                                   \
        char* Bs_ = As_ + 8192;                                             \
        const float cf_[4] = {(float)ci##S.x, (float)ci##S.y,               \
                              (float)ci##S.z, (float)ci##S.w};              \
        _Pragma("unroll")                                                   \
        for (int q = 0; q < 2; ++q) {                                       \
            const int row_ = rbase + 128 * q;                               \
            const float a_[4]  = {va##S[q].x, va##S[q].y, va##S[q].z, va##S[q].w}; \
            const float bb_[4] = {vb##S[q].x, vb##S[q].y, vb##S[q].z, vb##S[q].w}; \
            ushort4 pa_, pb_;                                               \
            unsigned short* pav_ = (unsigned short*)&pa_;                   \
            unsigned short* pbv_ = (unsigned short*)&pb_;                   \
            _Pragma("unroll")                                               \
            for (int j = 0; j < 4; ++j) {                                   \
                const float a2_ = a_[j] * a_[j];                            \
                const float b2_ = bb_[j] * bb_[j];                          \
                const float wb_ = cf_[j] * bb_[j];                          \
                sA[q] = fmaf(cf_[j], a_[j], sA[q]);                         \
                ssA[q] = fmaf(cf_[j], a2_, ssA[q]);                         \
                sB[q] = fmaf(cf_[j], bb_[j], sB[q]);                        \
                ssB[q] = fmaf(cf_[j], b2_, ssB[q]);                         \
                pav_[j] = f2bf(a_[j]);                                      \
                pbv_[j] = f2bf(wb_);                                        \
            }                                                               \
            const int off_ = (((cg >> 1) * 256 + row_) << 4) + ((cg & 1) << 3); \
            *(unsigned long long*)(As_ + off_) = *(unsigned long long*)&pa_; \
            *(unsigned long long*)(Bs_ + off_) = *(unsigned long long*)&pb_; \
        }                                                                   \
    }

    auto MFMA_STEP = [&](int buf) {
        const char* As = smem + buf * 16384;
        const char* Bs = As + 8192;
        s16x8 af[4], bfr[2];
#pragma unroll
        for (int rt = 0; rt < 4; ++rt) {
            const int row = 128 * wr + 32 * rt + l31;
            af[rt] = *(const s16x8*)(As + ((half * 256 + row) << 4));
        }
#pragma unroll
        for (int ct = 0; ct < 2; ++ct) {
            const int row = 64 * wc + 32 * ct + l31;
            bfr[ct] = *(const s16x8*)(Bs + ((half * 256 + row) << 4));
        }
#pragma unroll
        for (int rt = 0; rt < 4; ++rt)
#pragma unroll
            for (int ct = 0; ct < 2; ++ct)
                acc[rt][ct] = __builtin_amdgcn_mfma_f32_32x32x16_bf16(
                    af[rt], bfr[ct], acc[rt][ct], 0, 0, 0);
    };

    // Prologue
    LOAD_SET(0, 0)
    CONV_SET(0, 0)
    LOAD_SET(1, 1)
    LOAD_SET(0, 2)
    BAR_SOFT();

    for (int kt = 0; kt < kNIter; kt += 2) {
        CONV_SET(1, 1)
        if (kt + 3 < kNIter) LOAD_SET(1, kt + 3)
        MFMA_STEP(0);
        BAR_SOFT();

        if (kt + 2 < kNIter) CONV_SET(0, 0)
        if (kt + 4 < kNIter) LOAD_SET(0, kt + 4)
        MFMA_STEP(1);
        BAR_SOFT();
    }
    __syncthreads();   // full drain before smem reuse

    // 256x256 partial Gram in bf16
    __hip_bfloat16* out = partial + (size_t)bx * (kD * kD);
#pragma unroll
    for (int rt = 0; rt < 4; ++rt)
#pragma unroll
        for (int ct = 0; ct < 2; ++ct)
#pragma unroll
            for (int r = 0; r < 16; ++r) {
                const int row = 128 * wr + 32 * rt + (r & 3) + 8 * (r >> 2) + 4 * half;
                const int col = 64 * wc + 32 * ct + l31;
                ((unsigned short*)out)[row * kD + col] = f2bf(acc[rt][ct][r]);
            }

    // stats partial reduce via (dead) LDS: sd[256 rows][4 cg][4 kinds] = 16KB
    float* sd = (float*)smem;
#pragma unroll
    for (int q = 0; q < 2; ++q) {
        const int row = rbase + 128 * q;
        float* p = sd + (row * 4 + cg) * 4;
        p[0] = sA[q]; p[1] = ssA[q]; p[2] = sB[q]; p[3] = ssB[q];
    }
    __syncthreads();
    {
        const int row = t >> 1;
        const int pair = t & 1;
        float a0 = 0.f, a1 = 0.f;
#pragma unroll
        for (int g = 0; g < 4; ++g) {
            a0 += sd[(row * 4 + g) * 4 + 2 * pair];
            a1 += sd[(row * 4 + g) * 4 + 2 * pair + 1];
        }
        float* p = statsPart + ((size_t)bx * kD + row) * 4;
        p[2 * pair] = a0;
        p[2 * pair + 1] = a1;
    }
#undef LOAD_SET
#undef CONV_SET
}

// ---------------------------------------------------------------------------
// Kernel 3: reduce bf16 partial Grams (512 x [256][256]) -> G f32;
// statsPart -> statsRed.  Grid 256 (one block per output row d).
// Thread layout: 32 e-threads (8 cols each, 16B loads) x 8 c-groups.
// ---------------------------------------------------------------------------
__global__ __launch_bounds__(256) void reduce_gram_kernel(
    const __hip_bfloat16* __restrict__ partial, const float* __restrict__ statsPart,
    float* __restrict__ G, float* __restrict__ statsRed)
{
    const int d = blockIdx.x;
    const int t = threadIdx.x;
    const int eg = t & 31;          // e-group: cols eg*8..+8
    const int cgp = t >> 5;         // 0..7

    float fa[8];
#pragma unroll
    for (int j = 0; j < 8; ++j) fa[j] = 0.f;
    const unsigned short* pbase = (const unsigned short*)partial + d * kD + eg * 8;
    for (int c0 = 0; c0 < kNBlk / 8; ++c0) {
        const int c = c0 * 8 + cgp;
        const s16x8 v = *(const s16x8*)(pbase + (size_t)c * (kD * kD));
#pragma unroll
        for (int j = 0; j < 8; ++j)
            fa[j] += bf2f(((const unsigned short*)&v)[j]);
    }
    __shared__ float sd[8][256];
#pragma unroll
    for (int j = 0; j < 8; ++j) sd[cgp][eg * 8 + j] = fa[j];
    __syncthreads();
    {
        const int e = t;
        float s = 0.f;
#pragma unroll
        for (int g = 0; g < 8; ++g) s += sd[g][e];
        G[d * kD + e] = s;
    }

    // stats: thread t accumulates slabs t, t+256 of row d, then reduce
    float x0 = 0.f, x1 = 0.f, x2 = 0.f, x3 = 0.f;
#pragma unroll
    for (int c = t; c < kNBlk; c += 256) {
        const float4 v = *(const float4*)(statsPart + ((size_t)c * kD + d) * 4);
        x0 += v.x; x1 += v.y; x2 += v.z; x3 += v.w;
    }
#pragma unroll
    for (int o = 32; o; o >>= 1) {
        x0 += __shfl_down(x0, o);
        x1 += __shfl_down(x1, o);
        x2 += __shfl_down(x2, o);
        x3 += __shfl_down(x3, o);
    }
    __shared__ float r[4][4];
    if ((t & 63) == 0) {
        r[t >> 6][0] = x0; r[t >> 6][1] = x1;
        r[t >> 6][2] = x2; r[t >> 6][3] = x3;
    }
    __syncthreads();
    if (t < 4) {
        statsRed[d * 4 + t] = r[0][t] + r[1][t] + r[2][t] + r[3][t];
    }
}

// ---------------------------------------------------------------------------
// Kernel 4: final loss (single block).
// ---------------------------------------------------------------------------
__global__ __launch_bounds__(256) void loss_kernel(
    const float* __restrict__ G, const float* __restrict__ statsRed,
    float* __restrict__ out)
{
    __shared__ float muA[kD], isA[kD], muB[kD], isB[kD];
    const int t = threadIdx.x;
    const float4 v = *(const float4*)(statsRed + t * 4);
    const float n = (float)kN;
    const float mA = v.x / n, mB = v.z / n;
    const float vA = (v.y - n * mA * mA) / (n - 1.f);
    const float vB = (v.w - n * mB * mB) / (n - 1.f);
    const float sdA = fmaxf(sqrtf(fmaxf(vA, 0.f)), 1e-6f);
    const float sdB = fmaxf(sqrtf(fmaxf(vB, 0.f)), 1e-6f);
    muA[t] = mA; isA[t] = 1.f / sdA;
    muB[t] = mB; isB[t] = 1.f / sdB;
    __syncthreads();

    float acc = 0.f;
    for (int d = 0; d < kD; ++d) {
        const int e = t;
        const float c = (G[d * kD + e] / n - muA[d] * muB[e]) * isA[d] * isB[e];
        if (d == e) { const float u = 1.f - c; acc += u * u; }
        else        { acc += kLam * c * c; }
    }
#pragma unroll
    for (int o = 32; o; o >>= 1) acc += __shfl_down(acc, o);
    __shared__ float r[4];
    if ((t & 63) == 0) r[t >> 6] = acc;
    __syncthreads();
    if (t == 0) out[0] = r[0] + r[1] + r[2] + r[3];
}

// ---------------------------------------------------------------------------
extern "C" void kernel_launch(void* const* d_in, const int* in_sizes, int n_in,
                              void* d_out, int out_size, void* d_ws, size_t ws_size,
                              hipStream_t stream) {
    const float* z  = (const float*)d_in[0];
    const float* zp = (const float*)d_in[1];
    const int* flat_idx = (const int*)d_in[2];
    float* out = (float*)d_out;

    char* ws = (char*)d_ws;
    // ws layout:
    //   [0, 1MB)        counts  int [16][16384]
    //   [1MB, 3MB)      statsPart f32 [512][256][4]
    //   [3MB, +4K)      statsRed f32 [256][4]
    //   [3MB+64K,+256K) G f32 [256][256]
    //   [16MB, 80MB)    partial bf16 [512][256][256]
    int* cnt = (int*)ws;
    float* statsPart = (float*)(ws + (size_t)1 * 1024 * 1024);
    float* statsRed  = (float*)(ws + (size_t)3 * 1024 * 1024);
    float* G = (float*)(ws + (size_t)3 * 1024 * 1024 + 64 * 1024);
    __hip_bfloat16* partial = (__hip_bfloat16*)(ws + (size_t)16 * 1024 * 1024);

    count_kernel<<<kB, 256, 0, stream>>>(flat_idx, cnt);
    fused_gram_kernel<<<kNBlk, 512, 0, stream>>>(z, zp, cnt, partial, statsPart);
    reduce_gram_kernel<<<kD, 256, 0, stream>>>(partial, statsPart, G, statsRed);
    loss_kernel<<<1, 256, 0, stream>>>(G, statsRed, out);
}